// Round 12
// baseline (65.405 us; speedup 1.0000x reference)
//
#include <hip/hip_runtime.h>

// Sliding-window attention, window=127 (+-63), B=4 L=4096 NH=16 H=64, fp32 in/out.
// Round-12: R10 structure, 768-thread blocks -> 24 waves/CU (occ 36% -> ~70%).
//  - 12 waves: query tile qt=w&3, part=w>>2 owns key tiles {qt,qt+1 | qt+2,qt+3 | qt+4}.
//  - LDS exactly 80KB (Q16+K32+V32) -> 2 blocks/CU; launch_bounds(768,6) -> 84-VGPR
//    budget (kernel historically needs 52-64; no R3 spill trap).
//  - Epilogue: parts 1,2 publish partial O^T + dw into dead Q/K/V LDS (two disjoint
//    32KB buffers + 2x512B D rows); part 0 combines, dinv lane-local, direct float4
//    stores (R9-verified clean 65.5MB write-combining).
//  - Staging: flat-guarded item loop (8192 items: Q 2048, K 4096, V 2048 dual-row),
//    same coalesced float4 / swizzled-LDS patterns as R10.
//  - FROZEN RULE (R3/R5): no register prefetch pinned across MFMA, no sched_barrier.

typedef _Float16 f16;
typedef _Float16 f16x2  __attribute__((ext_vector_type(2)));
typedef _Float16 f16x4  __attribute__((ext_vector_type(4)));
typedef _Float16 f16x8  __attribute__((ext_vector_type(8)));
typedef float    f32x16 __attribute__((ext_vector_type(16)));
typedef int      int4v  __attribute__((ext_vector_type(4)));

constexpr int NB = 4, L = 4096, NH = 16, H = 64;
constexpr int CQ = 128, NC = L / CQ, KW = 256, WR = 63;
constexpr int RS = NH * H;   // seq-row stride in floats

constexpr int Q_OFF = 0;         // [128][64] f16, 128B rows, swizzled (16 KB)
constexpr int K_OFF = 16384;     // [256][64] f16, 128B rows, swizzled (32 KB)
constexpr int V_OFF = 49152;     // [64][256] f16 transposed, 512B rows, swizzled (32 KB)
constexpr int LDS_BYTES = 81920; // 80 KiB -> exactly 2 blocks/CU
// post-compute aliases (everything dead after b1):
constexpr int X1_OFF = 0;        // part-1 partial O^T [64][128] f32 (32 KB)
constexpr int X2_OFF = 32768;    // part-2 partial O^T [64][128] f32 (32 KB)
constexpr int D1_OFF = 65536;    // part-1 partial denom [128] f32
constexpr int D2_OFF = 66048;    // part-2 partial denom [128] f32

#define DEV static __device__ __forceinline__

DEV int iclamp(int x, int lo, int hi) { return x < lo ? lo : (x > hi ? hi : x); }

DEV float fexp2(float x) {
#if __has_builtin(__builtin_amdgcn_exp2f)
    return __builtin_amdgcn_exp2f(x);
#else
    return exp2f(x);
#endif
}

DEV int packh2(float a, float b) {
    f16x2 p; p.x = (f16)a; p.y = (f16)b;   // RNE casts
    return __builtin_bit_cast(int, p);
}

// byte offset in row-major [R][64] f16 tile (128B rows), bank-conflict swizzle
DEV int rmaddr(int base, int r, int colb) {
    return base + r * 128 + (colb ^ ((r & 7) << 4));
}

// byte offset of (row h, key byte kb) in transposed V_lds (512B rows)
DEV int vaddr(int h, int kb) {
    return V_OFF + ((h * 512 + kb) ^ ((((h & 7) ^ ((h >> 3) & 7))) << 4));
}

// After call: a = [a_lo | b_lo], b = [a_hi | b_hi]. HW-verified (R7+).
DEV void swap_halves(int& a, int& b) {
    asm volatile("v_permlane32_swap_b32 %0, %1" : "+v"(a), "+v"(b));
}

__global__ __launch_bounds__(768, 6)
void wattn_kernel(const float* __restrict__ q_, const float* __restrict__ k_,
                  const float* __restrict__ v_, float* __restrict__ o_)
{
    __shared__ alignas(16) char smem[LDS_BYTES];

    // XCD-aware swizzle: 2048 blocks, 8 XCDs, 2048%8==0 -> bijective
    const int bid = (int)blockIdx.x;
    const int wid = (bid & 7) * ((NB * NH * NC) / 8) + (bid >> 3);
    const int c = wid & (NC - 1);
    const int n = (wid >> 5) & (NH - 1);
    const int b = wid >> 9;

    const int t    = (int)threadIdx.x;
    const int lane = t & 63;
    const int w    = t >> 6;        // wave 0..11
    const int lq   = lane & 31;
    const int hi   = lane >> 5;
    const int qt   = w & 3;         // query tile 0..3
    const int part = w >> 2;        // 0: tiles {qt,qt+1}, 1: {qt+2,qt+3}, 2: {qt+4}

    const int kg0 = c * CQ - WR;                       // global seq row of window key j=0
    const size_t bn = ((size_t)b * L * NH + n) * H;    // element offset of (b,0,n,0)
    const float qs = 0.125f * 1.44269504088896f;       // h^-0.5 * log2(e)

    // ---- staging: flat-guarded item loop (items: Q 0..2047, K 2048..6143, V 6144..8191) ----
    #pragma unroll
    for (int it = 0; it < 11; ++it) {
        int flat = it * 768 + t;
        if (flat < 2048) {
            int r  = flat >> 4;
            int cb = (flat & 15) << 3;
            float4 x = *(const float4*)(q_ + bn + (size_t)(c * CQ + r) * RS + ((flat & 15) << 2));
            *(f16x4*)(smem + rmaddr(Q_OFF, r, cb)) =
                (f16x4){(f16)(x.x * qs), (f16)(x.y * qs), (f16)(x.z * qs), (f16)(x.w * qs)};
        } else if (flat < 6144) {
            int j  = flat - 2048;
            int r  = j >> 4;
            int cb = (j & 15) << 3;
            int kr = iclamp(kg0 + r, 0, L - 1);
            float4 x = *(const float4*)(k_ + bn + (size_t)kr * RS + ((j & 15) << 2));
            *(f16x4*)(smem + rmaddr(K_OFF, r, cb)) =
                (f16x4){(f16)x.x, (f16)x.y, (f16)x.z, (f16)x.w};
        } else if (flat < 8192) {
            int j   = flat - 6144;
            int r0  = (j >> 4) << 1;
            int h4  = (j & 15) << 2;
            int kr0 = iclamp(kg0 + r0,     0, L - 1);
            int kr1 = iclamp(kg0 + r0 + 1, 0, L - 1);
            float4 v0 = *(const float4*)(v_ + bn + (size_t)kr0 * RS + h4);
            float4 v1 = *(const float4*)(v_ + bn + (size_t)kr1 * RS + h4);
            int kb = r0 * 2;
            *(f16x2*)(smem + vaddr(h4 + 0, kb)) = (f16x2){(f16)v0.x, (f16)v1.x};
            *(f16x2*)(smem + vaddr(h4 + 1, kb)) = (f16x2){(f16)v0.y, (f16)v1.y};
            *(f16x2*)(smem + vaddr(h4 + 2, kb)) = (f16x2){(f16)v0.z, (f16)v1.z};
            *(f16x2*)(smem + vaddr(h4 + 3, kb)) = (f16x2){(f16)v0.w, (f16)v1.w};
        }
    }

    // window mask bounds: allowed local keys j with j-iq in [0,126] and kg0+j in [0,L)
    const int iq  = qt * 32 + lq;
    const int jlo = (c == 0) ? WR : 0;
    const int jhi = (KW < L - kg0) ? KW : (L - kg0);
    const int lo  = (iq > jlo) ? iq : jlo;
    const int hb  = (iq + 126 < jhi - 1) ? (iq + 126) : (jhi - 1);
    const unsigned span = (unsigned)(hb - lo);

    f32x16 o0, o1;   // O^T fragments: lane holds row q=lq, h = (r&3)+8(r>>2)+4hi (+32 for o1)
    #pragma unroll
    for (int r = 0; r < 16; ++r) { o0[r] = 0.f; o1[r] = 0.f; }
    float dsum = 0.f;

    __syncthreads();   // b0: staging complete

    // ---- Q fragments from LDS (B-operand: lane holds Q[q=lq][h=16tq+8hi+j]) ----
    f16x8 qf[4];
    #pragma unroll
    for (int tq = 0; tq < 4; ++tq)
        qf[tq] = *(const f16x8*)(smem + rmaddr(Q_OFF, qt * 32 + lq, 32 * tq + 16 * hi));

    auto body = [&](int kt) {
        // K fragments (A-operand: lane holds K[k=kt*32+lq][h=16tq+8hi+j])
        f16x8 kf[4];
        #pragma unroll
        for (int tq = 0; tq < 4; ++tq)
            kf[tq] = *(const f16x8*)(smem + rmaddr(K_OFF, kt * 32 + lq, 32 * tq + 16 * hi));

        // S^T tile = K_tile(32k x 64h) . Q^T
        f32x16 s;
        #pragma unroll
        for (int r = 0; r < 16; ++r) s[r] = 0.f;
        #pragma unroll
        for (int tq = 0; tq < 4; ++tq)
            s = __builtin_amdgcn_mfma_f32_32x32x16_f16(kf[tq], qf[tq], s, 0, 0, 0);

        // mask + exp2 + denominator (per-lane: q = lq)
        const int jb = kt * 32 + 4 * hi;
        float pe[16];
        #pragma unroll
        for (int r = 0; r < 16; ++r) {
            int j = jb + (r & 3) + ((r >> 2) << 3);      // D-row -> local key index
            float e = fexp2(s[r]);
            e = ((unsigned)(j - lo) <= span) ? e : 0.f;
            dsum += e;
            pe[r] = e;
        }
        // P fragments: pack to f16 pairs, exchange across lane halves
        int d0 = packh2(pe[0],  pe[1]),  d1 = packh2(pe[2],  pe[3]);
        int d2 = packh2(pe[4],  pe[5]),  d3 = packh2(pe[6],  pe[7]);
        int d4 = packh2(pe[8],  pe[9]),  d5 = packh2(pe[10], pe[11]);
        int d6 = packh2(pe[12], pe[13]), d7 = packh2(pe[14], pe[15]);
        swap_halves(d0, d2); swap_halves(d1, d3);
        swap_halves(d4, d6); swap_halves(d5, d7);
        f16x8 pa0 = __builtin_bit_cast(f16x8, (int4v){d0, d1, d2, d3});   // keys kt*32 + 0..15
        f16x8 pa1 = __builtin_bit_cast(f16x8, (int4v){d4, d5, d6, d7});   // keys kt*32 + 16..31

        // PV flipped: O^T[h][q] += V^T . P  (vb as A, pa as B)
        const int kb = kt * 64 + hi * 16;
        f16x8 vb00 = *(const f16x8*)(smem + vaddr(lq,      kb));
        f16x8 vb01 = *(const f16x8*)(smem + vaddr(lq,      kb + 32));
        f16x8 vb10 = *(const f16x8*)(smem + vaddr(32 + lq, kb));
        f16x8 vb11 = *(const f16x8*)(smem + vaddr(32 + lq, kb + 32));
        o0 = __builtin_amdgcn_mfma_f32_32x32x16_f16(vb00, pa0, o0, 0, 0, 0);
        o0 = __builtin_amdgcn_mfma_f32_32x32x16_f16(vb01, pa1, o0, 0, 0, 0);
        o1 = __builtin_amdgcn_mfma_f32_32x32x16_f16(vb10, pa0, o1, 0, 0, 0);
        o1 = __builtin_amdgcn_mfma_f32_32x32x16_f16(vb11, pa1, o1, 0, 0, 0);
    };

    // 3-way key-split over the 5 tiles of query tile qt
    if (part == 0)      { body(qt);     body(qt + 1); }
    else if (part == 1) { body(qt + 2); body(qt + 3); }
    else                { body(qt + 4); }

    // per-query partial denominator (q = lq lane-local in O^T orientation)
    float dw = dsum + __shfl_xor(dsum, 32, 64);

    __syncthreads();   // b1: ALL compute done; Q/K/V LDS dead -> reuse for exchange

    if (part == 1) {
        float* X = (float*)(smem + X1_OFF);
        #pragma unroll
        for (int r = 0; r < 16; ++r) {
            int h = (r & 3) + ((r >> 2) << 3) + 4 * hi;
            X[h * 128 + iq]        = o0[r];
            X[(32 + h) * 128 + iq] = o1[r];
        }
        if (lane < 32) ((float*)(smem + D1_OFF))[iq] = dw;
    } else if (part == 2) {
        float* X = (float*)(smem + X2_OFF);
        #pragma unroll
        for (int r = 0; r < 16; ++r) {
            int h = (r & 3) + ((r >> 2) << 3) + 4 * hi;
            X[h * 128 + iq]        = o0[r];
            X[(32 + h) * 128 + iq] = o1[r];
        }
        if (lane < 32) ((float*)(smem + D2_OFF))[iq] = dw;
    }
    __syncthreads();   // b2: partials visible

    if (part == 0) {
        const float* X1 = (const float*)(smem + X1_OFF);
        const float* X2 = (const float*)(smem + X2_OFF);
        float dinv = 1.0f / (dw + ((const float*)(smem + D1_OFF))[iq]
                                + ((const float*)(smem + D2_OFF))[iq]);
        const size_t ob = ((size_t)b * L + (size_t)c * CQ) * RS + (size_t)n * H;
        float* orow = o_ + ob + (size_t)iq * RS;
        #pragma unroll
        for (int m = 0; m < 4; ++m) {
            int h0 = 8 * m + 4 * hi;
            float4 v0, v1;
            v0.x = (o0[4 * m + 0] + X1[(h0 + 0) * 128 + iq] + X2[(h0 + 0) * 128 + iq]) * dinv;
            v0.y = (o0[4 * m + 1] + X1[(h0 + 1) * 128 + iq] + X2[(h0 + 1) * 128 + iq]) * dinv;
            v0.z = (o0[4 * m + 2] + X1[(h0 + 2) * 128 + iq] + X2[(h0 + 2) * 128 + iq]) * dinv;
            v0.w = (o0[4 * m + 3] + X1[(h0 + 3) * 128 + iq] + X2[(h0 + 3) * 128 + iq]) * dinv;
            v1.x = (o1[4 * m + 0] + X1[(32 + h0 + 0) * 128 + iq] + X2[(32 + h0 + 0) * 128 + iq]) * dinv;
            v1.y = (o1[4 * m + 1] + X1[(32 + h0 + 1) * 128 + iq] + X2[(32 + h0 + 1) * 128 + iq]) * dinv;
            v1.z = (o1[4 * m + 2] + X1[(32 + h0 + 2) * 128 + iq] + X2[(32 + h0 + 2) * 128 + iq]) * dinv;
            v1.w = (o1[4 * m + 3] + X1[(32 + h0 + 3) * 128 + iq] + X2[(32 + h0 + 3) * 128 + iq]) * dinv;
            *(float4*)(orow + h0)      = v0;
            *(float4*)(orow + 32 + h0) = v1;
        }
    }
}

extern "C" void kernel_launch(void* const* d_in, const int* in_sizes, int n_in,
                              void* d_out, int out_size, void* d_ws, size_t ws_size,
                              hipStream_t stream) {
    const float* q = (const float*)d_in[0];
    const float* k = (const float*)d_in[1];
    const float* v = (const float*)d_in[2];
    float* o = (float*)d_out;
    (void)in_sizes; (void)n_in; (void)out_size; (void)d_ws; (void)ws_size;
    wattn_kernel<<<dim3(NB * NH * NC), dim3(768), 0, stream>>>(q, k, v, o);
}

// Round 13
// 55.024 us; speedup vs baseline: 1.1887x; 1.1887x over previous
//
#include <hip/hip_runtime.h>

// Sliding-window attention, window=127 (+-63), B=4 L=4096 NH=16 H=64, fp32 in/out.
// Round-13: traffic cut. Theory: plateau at ~49us = 384MB through-cache at ~7.8TB/s
// (occupancy 19-55% all gave 49-65us -> CU-side levers exhausted; memory system is
// the saturated resource). CQ 128->256 cuts K/V window duplication 2.0x -> 1.5x:
// 384 -> 320MB -> predicted ~42us.
//  - 1024 blocks x 512 thr; 8 waves x 32 queries; tiles w..w+4 of 12 (KW=384).
//  - Two-phase rolling LDS (64KB total -> 2 blocks/CU): phase A = window rows 0..255
//    (K 32KB + V^T 32KB), phase B = rows 256..383 overwrite DEAD tiles 0..3 slots;
//    uniform (kt&7) addressing on the read side. Waves 0..3 finish after A (their 5
//    tiles are all <8); waves 4..7 finish tiles >=8 after B.
//  - No key-split -> no partial exchange; R9 epilogue (lane-local dinv, direct float4
//    stores, write-combining verified clean).
//  - Q direct strided prologue loads (R11-proven correct); K/V staged coalesced.
//  - FROZEN RULE (R3/R5): no register prefetch pinned across MFMA, no sched_barrier.

typedef _Float16 f16;
typedef _Float16 f16x2  __attribute__((ext_vector_type(2)));
typedef _Float16 f16x4  __attribute__((ext_vector_type(4)));
typedef _Float16 f16x8  __attribute__((ext_vector_type(8)));
typedef float    f32x16 __attribute__((ext_vector_type(16)));
typedef int      int4v  __attribute__((ext_vector_type(4)));

constexpr int NB = 4, L = 4096, NH = 16, H = 64;
constexpr int CQ = 256, NC = L / CQ, KW = 384, WR = 63;
constexpr int RS = NH * H;   // seq-row stride in floats

constexpr int K_OFF = 0;         // [256][64] f16 rows (128B, swizzled): resident rows (kt&7)*32+..
constexpr int V_OFF = 32768;     // [64][256] f16 transposed (512B rows, swizzled): cols (kt&7)*32+..
constexpr int LDS_BYTES = 65536; // 64 KiB -> 2 blocks/CU

#define DEV static __device__ __forceinline__

DEV int iclamp(int x, int lo, int hi) { return x < lo ? lo : (x > hi ? hi : x); }

DEV float fexp2(float x) {
#if __has_builtin(__builtin_amdgcn_exp2f)
    return __builtin_amdgcn_exp2f(x);
#else
    return exp2f(x);
#endif
}

DEV int packh2(float a, float b) {
    f16x2 p; p.x = (f16)a; p.y = (f16)b;   // RNE casts
    return __builtin_bit_cast(int, p);
}

// K: byte offset for resident row rr (0..255), byte col (0..127), swizzled
DEV int kaddr(int rr, int colb) {
    return K_OFF + rr * 128 + (colb ^ ((rr & 7) << 4));
}

// V: byte offset of (row h, resident key byte kb 0..511), swizzled
DEV int vaddr(int h, int kb) {
    return V_OFF + ((h * 512 + kb) ^ ((((h & 7) ^ ((h >> 3) & 7))) << 4));
}

// After call: a = [a_lo | b_lo], b = [a_hi | b_hi]. HW-verified (R7+).
DEV void swap_halves(int& a, int& b) {
    asm volatile("v_permlane32_swap_b32 %0, %1" : "+v"(a), "+v"(b));
}

__global__ __launch_bounds__(512, 4)
void wattn_kernel(const float* __restrict__ q_, const float* __restrict__ k_,
                  const float* __restrict__ v_, float* __restrict__ o_)
{
    __shared__ alignas(16) char smem[LDS_BYTES];

    // XCD-aware swizzle: 1024 blocks, 8 XCDs, 1024%8==0 -> bijective
    const int bid = (int)blockIdx.x;
    const int wid = (bid & 7) * ((NB * NH * NC) / 8) + (bid >> 3);
    const int c = wid & (NC - 1);
    const int n = (wid >> 4) & (NH - 1);
    const int b = wid >> 8;

    const int t    = (int)threadIdx.x;
    const int lane = t & 63;
    const int w    = t >> 6;        // wave 0..7 = query tile (32 rows each)
    const int lq   = lane & 31;
    const int hi   = lane >> 5;

    const int kg0 = c * CQ - WR;                       // global seq row of window key j=0
    const size_t bn = ((size_t)b * L * NH + n) * H;    // element offset of (b,0,n,0)
    const float qs = 0.125f * 1.44269504088896f;       // h^-0.5 * log2(e)

    // staging thread->element mapping: 16 threads per 256B source row
    const int h4 = (t & 15) << 2;    // float col 0,4,..,60
    const int cb = h4 << 1;          // f16 byte col
    const int ru = t >> 4;           // 0..31

    // ---- Q prologue: direct strided loads -> scaled f16 fragments ----
    const int iq = w * 32 + lq;
    const float* qrow = q_ + bn + (size_t)(c * CQ + iq) * RS + hi * 8;
    f16x8 qf[4];
    #pragma unroll
    for (int tq = 0; tq < 4; ++tq) {
        float4 a  = *(const float4*)(qrow + tq * 16);
        float4 b2 = *(const float4*)(qrow + tq * 16 + 4);
        qf[tq] = (f16x8){(f16)(a.x * qs),  (f16)(a.y * qs),  (f16)(a.z * qs),  (f16)(a.w * qs),
                         (f16)(b2.x * qs), (f16)(b2.y * qs), (f16)(b2.z * qs), (f16)(b2.w * qs)};
    }

    // ---- phase A stage: window rows 0..255 (K rows + V^T cols) ----
    #pragma unroll
    for (int p = 0; p < 8; ++p) {
        int r  = ru + p * 32;
        int kr = iclamp(kg0 + r, 0, L - 1);
        float4 x = *(const float4*)(k_ + bn + (size_t)kr * RS + h4);
        *(f16x4*)(smem + kaddr(r, cb)) = (f16x4){(f16)x.x, (f16)x.y, (f16)x.z, (f16)x.w};
    }
    #pragma unroll
    for (int p = 0; p < 4; ++p) {
        int r0  = ru * 2 + p * 64;
        int kr0 = iclamp(kg0 + r0,     0, L - 1);
        int kr1 = iclamp(kg0 + r0 + 1, 0, L - 1);
        float4 v0 = *(const float4*)(v_ + bn + (size_t)kr0 * RS + h4);
        float4 v1 = *(const float4*)(v_ + bn + (size_t)kr1 * RS + h4);
        int kb = r0 * 2;
        *(f16x2*)(smem + vaddr(h4 + 0, kb)) = (f16x2){(f16)v0.x, (f16)v1.x};
        *(f16x2*)(smem + vaddr(h4 + 1, kb)) = (f16x2){(f16)v0.y, (f16)v1.y};
        *(f16x2*)(smem + vaddr(h4 + 2, kb)) = (f16x2){(f16)v0.z, (f16)v1.z};
        *(f16x2*)(smem + vaddr(h4 + 3, kb)) = (f16x2){(f16)v0.w, (f16)v1.w};
    }

    // window mask bounds: allowed local keys j with j-iq in [0,126] and kg0+j in [0,L)
    const int jlo = (c == 0) ? WR : 0;
    const int jhi = (KW < L - kg0) ? KW : (L - kg0);
    const int lo  = (iq > jlo) ? iq : jlo;
    const int hb  = (iq + 126 < jhi - 1) ? (iq + 126) : (jhi - 1);
    const unsigned span = (unsigned)(hb - lo);

    f32x16 o0, o1;   // O^T fragments: lane holds row q=lq(+w*32), h = (r&3)+8(r>>2)+4hi (+32 for o1)
    #pragma unroll
    for (int r = 0; r < 16; ++r) { o0[r] = 0.f; o1[r] = 0.f; }
    float dsum = 0.f;

    auto body = [&](int kt) {
        const int rr = (kt & 7) * 32 + lq;     // resident K row
        f16x8 kf[4];
        #pragma unroll
        for (int tq = 0; tq < 4; ++tq)
            kf[tq] = *(const f16x8*)(smem + kaddr(rr, 32 * tq + 16 * hi));

        f32x16 s;
        #pragma unroll
        for (int r = 0; r < 16; ++r) s[r] = 0.f;
        #pragma unroll
        for (int tq = 0; tq < 4; ++tq)
            s = __builtin_amdgcn_mfma_f32_32x32x16_f16(kf[tq], qf[tq], s, 0, 0, 0);

        const int jb = kt * 32 + 4 * hi;
        float pe[16];
        #pragma unroll
        for (int r = 0; r < 16; ++r) {
            int j = jb + (r & 3) + ((r >> 2) << 3);      // D-row -> local key index
            float e = fexp2(s[r]);
            e = ((unsigned)(j - lo) <= span) ? e : 0.f;
            dsum += e;
            pe[r] = e;
        }
        int d0 = packh2(pe[0],  pe[1]),  d1 = packh2(pe[2],  pe[3]);
        int d2 = packh2(pe[4],  pe[5]),  d3 = packh2(pe[6],  pe[7]);
        int d4 = packh2(pe[8],  pe[9]),  d5 = packh2(pe[10], pe[11]);
        int d6 = packh2(pe[12], pe[13]), d7 = packh2(pe[14], pe[15]);
        swap_halves(d0, d2); swap_halves(d1, d3);
        swap_halves(d4, d6); swap_halves(d5, d7);
        f16x8 pa0 = __builtin_bit_cast(f16x8, (int4v){d0, d1, d2, d3});   // keys kt*32 + 0..15
        f16x8 pa1 = __builtin_bit_cast(f16x8, (int4v){d4, d5, d6, d7});   // keys kt*32 + 16..31

        // PV flipped: O^T[h][q] += V^T . P  (vb as A, pa as B)
        const int kb = (kt & 7) * 64 + hi * 16;          // resident V col byte
        f16x8 vb00 = *(const f16x8*)(smem + vaddr(lq,      kb));
        f16x8 vb01 = *(const f16x8*)(smem + vaddr(lq,      kb + 32));
        f16x8 vb10 = *(const f16x8*)(smem + vaddr(32 + lq, kb));
        f16x8 vb11 = *(const f16x8*)(smem + vaddr(32 + lq, kb + 32));
        o0 = __builtin_amdgcn_mfma_f32_32x32x16_f16(vb00, pa0, o0, 0, 0, 0);
        o0 = __builtin_amdgcn_mfma_f32_32x32x16_f16(vb01, pa1, o0, 0, 0, 0);
        o1 = __builtin_amdgcn_mfma_f32_32x32x16_f16(vb10, pa0, o1, 0, 0, 0);
        o1 = __builtin_amdgcn_mfma_f32_32x32x16_f16(vb11, pa1, o1, 0, 0, 0);
    };

    auto epilogue = [&]() {
        float dtot = dsum + __shfl_xor(dsum, 32, 64);
        float dinv = 1.0f / dtot;
        const size_t ob = ((size_t)b * L + (size_t)c * CQ) * RS + (size_t)n * H;
        float* orow = o_ + ob + (size_t)iq * RS;
        #pragma unroll
        for (int m = 0; m < 4; ++m) {
            int h0 = 8 * m + 4 * hi;
            float4 v0, v1;
            v0.x = o0[4 * m + 0] * dinv;  v0.y = o0[4 * m + 1] * dinv;
            v0.z = o0[4 * m + 2] * dinv;  v0.w = o0[4 * m + 3] * dinv;
            v1.x = o1[4 * m + 0] * dinv;  v1.y = o1[4 * m + 1] * dinv;
            v1.z = o1[4 * m + 2] * dinv;  v1.w = o1[4 * m + 3] * dinv;
            *(float4*)(orow + h0)      = v0;
            *(float4*)(orow + 32 + h0) = v1;
        }
    };

    __syncthreads();   // b0: phase-A staging complete

    // ---- phase A compute: tiles w..min(w+4,7) ----
    {
        const int kend = (w + 4 < 7) ? (w + 4) : 7;
        for (int kt = w; kt <= kend; ++kt) body(kt);
    }
    if (w < 4) epilogue();   // waves 0..3: all 5 tiles done -> store now (overlaps others)

    __syncthreads();   // b1: all phase-A LDS reads done; tiles 0..3 slots dead

    // ---- phase B stage: window rows 256..383 into dead tile-0..3 slots ----
    #pragma unroll
    for (int p = 0; p < 4; ++p) {
        int r  = 256 + ru + p * 32;
        int kr = iclamp(kg0 + r, 0, L - 1);
        float4 x = *(const float4*)(k_ + bn + (size_t)kr * RS + h4);
        *(f16x4*)(smem + kaddr(r - 256, cb)) = (f16x4){(f16)x.x, (f16)x.y, (f16)x.z, (f16)x.w};
    }
    #pragma unroll
    for (int p = 0; p < 2; ++p) {
        int r0  = 256 + ru * 2 + p * 64;
        int kr0 = iclamp(kg0 + r0,     0, L - 1);
        int kr1 = iclamp(kg0 + r0 + 1, 0, L - 1);
        float4 v0 = *(const float4*)(v_ + bn + (size_t)kr0 * RS + h4);
        float4 v1 = *(const float4*)(v_ + bn + (size_t)kr1 * RS + h4);
        int kb = (r0 - 256) * 2;
        *(f16x2*)(smem + vaddr(h4 + 0, kb)) = (f16x2){(f16)v0.x, (f16)v1.x};
        *(f16x2*)(smem + vaddr(h4 + 1, kb)) = (f16x2){(f16)v0.y, (f16)v1.y};
        *(f16x2*)(smem + vaddr(h4 + 2, kb)) = (f16x2){(f16)v0.z, (f16)v1.z};
        *(f16x2*)(smem + vaddr(h4 + 3, kb)) = (f16x2){(f16)v0.w, (f16)v1.w};
    }

    __syncthreads();   // b2: phase-B rows visible

    // ---- phase B compute: waves 4..7 finish tiles 8..w+4 ----
    if (w >= 4) {
        for (int kt = 8; kt <= w + 4; ++kt) body(kt);
        epilogue();
    }
}

extern "C" void kernel_launch(void* const* d_in, const int* in_sizes, int n_in,
                              void* d_out, int out_size, void* d_ws, size_t ws_size,
                              hipStream_t stream) {
    const float* q = (const float*)d_in[0];
    const float* k = (const float*)d_in[1];
    const float* v = (const float*)d_in[2];
    float* o = (float*)d_out;
    (void)in_sizes; (void)n_in; (void)out_size; (void)d_ws; (void)ws_size;
    wattn_kernel<<<dim3(NB * NH * NC), dim3(512), 0, stream>>>(q, k, v, o);
}

// Round 14
// 52.044 us; speedup vs baseline: 1.2567x; 1.0573x over previous
//
#include <hip/hip_runtime.h>

// Sliding-window attention, window=127 (+-63), B=4 L=4096 NH=16 H=64, fp32 in/out.
// Round-14: persistent chunk blocks + rolling K/V ring (the last macro lever).
//  - Block = (b, head, 4 consecutive 128-query chunks). K/V windows of consecutive
//    chunks overlap 128/256 rows: stage 8 tiles for chunk 0, then only 4 NEW tiles
//    per chunk (ring slot = G&7, R13-proven addressing). K/V traffic & staging ~-38%.
//  - Per chunk: {stage -> bar -> 4 waves x 5 tile-bodies + lane-local epilogue -> bar}.
//    Monolithic K+V resident (64KB) -- no R11 two-phase flaw, no R13 wave-split tail.
//  - Q direct strided prologue loads per chunk (R11-proven); no Q LDS.
//  - R9 epilogue: dinv lane-local, direct float4 stores (write-combining verified).
//  - 512 blocks x 256 thr; LDS 64KB -> exactly 2 resident blocks/CU (cross-block
//    phase desync is the latency-hiding mechanism; R12 proved occupancy isn't).
//  - FROZEN RULE (R3/R5): no register prefetch pinned across MFMA, no sched_barrier.

typedef _Float16 f16;
typedef _Float16 f16x2  __attribute__((ext_vector_type(2)));
typedef _Float16 f16x4  __attribute__((ext_vector_type(4)));
typedef _Float16 f16x8  __attribute__((ext_vector_type(8)));
typedef float    f32x16 __attribute__((ext_vector_type(16)));
typedef int      int4v  __attribute__((ext_vector_type(4)));

constexpr int NB = 4, L = 4096, NH = 16, H = 64;
constexpr int CQ = 128, NC = L / CQ, KW = 256, WR = 63;
constexpr int CPB = 4;                    // chunks per block
constexpr int NCG = NC / CPB;             // 8 chunk-groups per (b,n)
constexpr int NBLK = NB * NH * NCG;       // 512 blocks
constexpr int RS = NH * H;                // seq-row stride in floats

constexpr int K_OFF = 0;         // ring: 8 slots x [32][64] f16 rows (128B, swizzled) = 32KB
constexpr int V_OFF = 32768;     // ring: [64][8 slots x 64B] transposed (512B rows, swizzled) = 32KB
constexpr int LDS_BYTES = 65536; // 64 KiB -> 2 blocks/CU

#define DEV static __device__ __forceinline__

DEV int iclamp(int x, int lo, int hi) { return x < lo ? lo : (x > hi ? hi : x); }

DEV float fexp2(float x) {
#if __has_builtin(__builtin_amdgcn_exp2f)
    return __builtin_amdgcn_exp2f(x);
#else
    return exp2f(x);
#endif
}

DEV int packh2(float a, float b) {
    f16x2 p; p.x = (f16)a; p.y = (f16)b;   // RNE casts
    return __builtin_bit_cast(int, p);
}

// K: resident row rr = slot*32 + r (0..255), byte col (0..127), swizzled
DEV int kaddr(int rr, int colb) {
    return K_OFF + rr * 128 + (colb ^ ((rr & 7) << 4));
}

// V: (row h, resident key byte kb = slot*64 + 2*r), swizzled
DEV int vaddr(int h, int kb) {
    return V_OFF + ((h * 512 + kb) ^ ((((h & 7) ^ ((h >> 3) & 7))) << 4));
}

// After call: a = [a_lo | b_lo], b = [a_hi | b_hi]. HW-verified (R7+).
DEV void swap_halves(int& a, int& b) {
    asm volatile("v_permlane32_swap_b32 %0, %1" : "+v"(a), "+v"(b));
}

__global__ __launch_bounds__(256, 2)
void wattn_kernel(const float* __restrict__ q_, const float* __restrict__ k_,
                  const float* __restrict__ v_, float* __restrict__ o_)
{
    __shared__ alignas(16) char smem[LDS_BYTES];

    // XCD-aware swizzle: 512 blocks, 8 XCDs, 512%8==0 -> bijective
    const int bid = (int)blockIdx.x;
    const int wid = (bid & 7) * (NBLK / 8) + (bid >> 3);
    const int cg = wid & (NCG - 1);        // chunk group 0..7
    const int n  = (wid >> 3) & (NH - 1);
    const int b  = wid >> 7;
    const int c0 = cg * CPB;               // first chunk of this block

    const int t    = (int)threadIdx.x;
    const int lane = t & 63;
    const int w    = t >> 6;        // wave 0..3 = query tile within chunk
    const int lq   = lane & 31;
    const int hi   = lane >> 5;

    const size_t bn = ((size_t)b * L * NH + n) * H;    // element offset of (b,0,n,0)
    const float qs = 0.125f * 1.44269504088896f;       // h^-0.5 * log2(e)
    const int base = c0 * CQ - WR;                     // abs key row of block tile G=0, r=0

    // staging thread->element mapping: 16 threads per 256B source row
    const int h4 = (t & 15) << 2;    // float col 0,4,..,60
    const int cb = h4 << 1;          // f16 byte col
    const int ru = t >> 4;           // 0..15

    // stage one 32-row K/V tile with global index G into ring slot G&7
    auto stage_tile = [&](int G) {
        const int slot = G & 7;
        // K: 2 passes x 16 rows
        #pragma unroll
        for (int p = 0; p < 2; ++p) {
            int r  = ru + p * 16;
            int kr = iclamp(base + G * 32 + r, 0, L - 1);
            float4 x = *(const float4*)(k_ + bn + (size_t)kr * RS + h4);
            *(f16x4*)(smem + kaddr(slot * 32 + r, cb)) =
                (f16x4){(f16)x.x, (f16)x.y, (f16)x.z, (f16)x.w};
        }
        // V: dual-row, 1 pass covers 32 rows
        {
            int r0  = ru * 2;
            int kr0 = iclamp(base + G * 32 + r0,     0, L - 1);
            int kr1 = iclamp(base + G * 32 + r0 + 1, 0, L - 1);
            float4 v0 = *(const float4*)(v_ + bn + (size_t)kr0 * RS + h4);
            float4 v1 = *(const float4*)(v_ + bn + (size_t)kr1 * RS + h4);
            int kb = slot * 64 + r0 * 2;
            *(f16x2*)(smem + vaddr(h4 + 0, kb)) = (f16x2){(f16)v0.x, (f16)v1.x};
            *(f16x2*)(smem + vaddr(h4 + 1, kb)) = (f16x2){(f16)v0.y, (f16)v1.y};
            *(f16x2*)(smem + vaddr(h4 + 2, kb)) = (f16x2){(f16)v0.z, (f16)v1.z};
            *(f16x2*)(smem + vaddr(h4 + 3, kb)) = (f16x2){(f16)v0.w, (f16)v1.w};
        }
    };

    #pragma unroll 1
    for (int ci = 0; ci < CPB; ++ci) {
        const int c = c0 + ci;

        // ---- stage new ring tiles (8 for first chunk, 4 after) ----
        const int gA = (ci == 0) ? 0 : 4 * ci + 4;
        const int gB = 4 * ci + 7;
        for (int G = gA; G <= gB; ++G) stage_tile(G);

        // ---- Q fragments: direct strided loads, scaled f16 ----
        const int iq = w * 32 + lq;
        const float* qrow = q_ + bn + (size_t)(c * CQ + iq) * RS + hi * 8;
        f16x8 qf[4];
        #pragma unroll
        for (int tq = 0; tq < 4; ++tq) {
            float4 a  = *(const float4*)(qrow + tq * 16);
            float4 b2 = *(const float4*)(qrow + tq * 16 + 4);
            qf[tq] = (f16x8){(f16)(a.x * qs),  (f16)(a.y * qs),  (f16)(a.z * qs),  (f16)(a.w * qs),
                             (f16)(b2.x * qs), (f16)(b2.y * qs), (f16)(b2.z * qs), (f16)(b2.w * qs)};
        }

        // window mask bounds for this chunk
        const int kg0 = c * CQ - WR;
        const int jlo = (c == 0) ? WR : 0;
        const int jhi = (KW < L - kg0) ? KW : (L - kg0);
        const int lo  = (iq > jlo) ? iq : jlo;
        const int hb  = (iq + 126 < jhi - 1) ? (iq + 126) : (jhi - 1);
        const unsigned span = (unsigned)(hb - lo);

        f32x16 o0, o1;   // O^T fragments: lane = row q, h = (r&3)+8(r>>2)+4hi (+32 for o1)
        #pragma unroll
        for (int r = 0; r < 16; ++r) { o0[r] = 0.f; o1[r] = 0.f; }
        float dsum = 0.f;

        __syncthreads();   // staged tiles visible

        // ---- compute: local tiles t = w .. w+4 (global G = 4ci + t) ----
        for (int tl = w; tl <= w + 4; ++tl) {
            const int slot = (4 * ci + tl) & 7;
            const int rr   = slot * 32 + lq;
            f16x8 kf[4];
            #pragma unroll
            for (int tq = 0; tq < 4; ++tq)
                kf[tq] = *(const f16x8*)(smem + kaddr(rr, 32 * tq + 16 * hi));

            f32x16 s;
            #pragma unroll
            for (int r = 0; r < 16; ++r) s[r] = 0.f;
            #pragma unroll
            for (int tq = 0; tq < 4; ++tq)
                s = __builtin_amdgcn_mfma_f32_32x32x16_f16(kf[tq], qf[tq], s, 0, 0, 0);

            const int jb = tl * 32 + 4 * hi;
            float pe[16];
            #pragma unroll
            for (int r = 0; r < 16; ++r) {
                int j = jb + (r & 3) + ((r >> 2) << 3);      // D-row -> local key index
                float e = fexp2(s[r]);
                e = ((unsigned)(j - lo) <= span) ? e : 0.f;
                dsum += e;
                pe[r] = e;
            }
            int d0 = packh2(pe[0],  pe[1]),  d1 = packh2(pe[2],  pe[3]);
            int d2 = packh2(pe[4],  pe[5]),  d3 = packh2(pe[6],  pe[7]);
            int d4 = packh2(pe[8],  pe[9]),  d5 = packh2(pe[10], pe[11]);
            int d6 = packh2(pe[12], pe[13]), d7 = packh2(pe[14], pe[15]);
            swap_halves(d0, d2); swap_halves(d1, d3);
            swap_halves(d4, d6); swap_halves(d5, d7);
            f16x8 pa0 = __builtin_bit_cast(f16x8, (int4v){d0, d1, d2, d3});   // keys tl*32+0..15
            f16x8 pa1 = __builtin_bit_cast(f16x8, (int4v){d4, d5, d6, d7});   // keys tl*32+16..31

            // PV flipped: O^T[h][q] += V^T . P
            const int kb = slot * 64 + hi * 16;
            f16x8 vb00 = *(const f16x8*)(smem + vaddr(lq,      kb));
            f16x8 vb01 = *(const f16x8*)(smem + vaddr(lq,      kb + 32));
            f16x8 vb10 = *(const f16x8*)(smem + vaddr(32 + lq, kb));
            f16x8 vb11 = *(const f16x8*)(smem + vaddr(32 + lq, kb + 32));
            o0 = __builtin_amdgcn_mfma_f32_32x32x16_f16(vb00, pa0, o0, 0, 0, 0);
            o0 = __builtin_amdgcn_mfma_f32_32x32x16_f16(vb01, pa1, o0, 0, 0, 0);
            o1 = __builtin_amdgcn_mfma_f32_32x32x16_f16(vb10, pa0, o1, 0, 0, 0);
            o1 = __builtin_amdgcn_mfma_f32_32x32x16_f16(vb11, pa1, o1, 0, 0, 0);
        }

        // ---- epilogue: dinv lane-local, direct float4 stores ----
        {
            float dtot = dsum + __shfl_xor(dsum, 32, 64);
            float dinv = 1.0f / dtot;
            const size_t ob = ((size_t)b * L + (size_t)c * CQ) * RS + (size_t)n * H;
            float* orow = o_ + ob + (size_t)iq * RS;
            #pragma unroll
            for (int m = 0; m < 4; ++m) {
                int h0 = 8 * m + 4 * hi;
                float4 v0, v1;
                v0.x = o0[4 * m + 0] * dinv;  v0.y = o0[4 * m + 1] * dinv;
                v0.z = o0[4 * m + 2] * dinv;  v0.w = o0[4 * m + 3] * dinv;
                v1.x = o1[4 * m + 0] * dinv;  v1.y = o1[4 * m + 1] * dinv;
                v1.z = o1[4 * m + 2] * dinv;  v1.w = o1[4 * m + 3] * dinv;
                *(float4*)(orow + h0)      = v0;
                *(float4*)(orow + 32 + h0) = v1;
            }
        }

        __syncthreads();   // all ring reads done before next chunk overwrites slots
    }
}

extern "C" void kernel_launch(void* const* d_in, const int* in_sizes, int n_in,
                              void* d_out, int out_size, void* d_ws, size_t ws_size,
                              hipStream_t stream) {
    const float* q = (const float*)d_in[0];
    const float* k = (const float*)d_in[1];
    const float* v = (const float*)d_in[2];
    float* o = (float*)d_out;
    (void)in_sizes; (void)n_in; (void)out_size; (void)d_ws; (void)ws_size;
    wattn_kernel<<<dim3(NBLK), dim3(256), 0, stream>>>(q, k, v, o);
}